// Round 6
// baseline (163.990 us; speedup 1.0000x reference)
//
#include <hip/hip_runtime.h>

// WL-conv factorized:  out[b,c,n,k] = Y0 + e1[c,k]*Y1 + e2[c,k]*Y2 + e3[c,k]*Y3
// with Ym = M^m labels (M = thresholded adjacency, c-independent) and e_m the
// elementary symmetric polynomials of kernels[c,0..2,k]. Valid because all
// per-step operators (I + k_t ∘ M) commute.
//
// spmm on the matrix pipe, single-bf16 (error margin >500x vs threshold):
//  - block owns 32 rows x full s-range -> NO atomics, plain stores
//  - Y staged per 1024-s chunk in LDS [f][s] bf16 (stride 1032: bank-minimal)
//  - A-frags from mask bytes via in-register bit-spread (no LUT, no conflicts)
//  - passes chained through transposed bf16 Y^T [b][f][n] written in epilogue
//
// d_out (8 MB): TRANSPOSED packed bits (word-major), overwritten by combine.
// d_ws (>=4.5 MB): Y1|Y2|Y3 f32 (3 MB) then Y1T|Y2T|Y3T bf16 (1.5 MB).

#define BB 4
#define NN 4096
#define KK 16
#define CC 8
#define TT 3
#define WPR (NN / 64)
#define CHUNK 1024
#define LSTR 1032   // LDS row stride (shorts): 16B-aligned, banks f*4 mod 32

typedef unsigned long long u64;
typedef unsigned int u32;
typedef unsigned short u16;
typedef __attribute__((ext_vector_type(8))) short s16x8;
typedef __attribute__((ext_vector_type(4))) float f32x4v;

__device__ __forceinline__ u32 bf16_rne(float f) {
    u32 u = __float_as_uint(f);
    return (u + 0x7FFFu + ((u >> 16) & 1u)) >> 16;
}

// byte (8 mask bits) -> 8 bf16 {0,1} packed in s16x8 (elem i = bit i)
__device__ __forceinline__ s16x8 expand8(u32 byt) {
    u32 n0 = byt & 0xFu, n1 = (byt >> 4) & 0xFu;
    u32 t0 = (n0 * 0x204081u) & 0x01010101u;   // bytes = bits 0..3
    u32 t1 = (n1 * 0x204081u) & 0x01010101u;   // bytes = bits 4..7
    u32 m0 = (t0 << 7) - t0;                   // bytes 0x7F / 0
    u32 m1 = (t1 << 7) - t1;
    union { u32 w[4]; s16x8 v; } u;
#if __has_builtin(__builtin_amdgcn_perm)
    u.w[0] = __builtin_amdgcn_perm(0u, m0, 0x0C010C00u) << 7;  // b0|b1<<16
    u.w[1] = __builtin_amdgcn_perm(0u, m0, 0x0C030C02u) << 7;  // b2|b3
    u.w[2] = __builtin_amdgcn_perm(0u, m1, 0x0C010C00u) << 7;  // b4|b5
    u.w[3] = __builtin_amdgcn_perm(0u, m1, 0x0C030C02u) << 7;  // b6|b7
#else
    u.w[0] = ((m0 & 0x7Fu) | ((m0 & 0x7F00u) << 8)) << 7;
    u.w[1] = (((m0 >> 16) & 0x7Fu) | (((m0 >> 16) & 0x7F00u) << 8)) << 7;
    u.w[2] = ((m1 & 0x7Fu) | ((m1 & 0x7F00u) << 8)) << 7;
    u.w[3] = (((m1 >> 16) & 0x7Fu) | (((m1 >> 16) & 0x7F00u) << 8)) << 7;
#endif
    return u.v;
}

// ---------------------------------------------------------------- pack ------
// TRANSPOSED: bits[(b*WPR + w)*NN + n] bit j <-> (lig[b][n][w*64+j] >= 1)
__global__ void pack_kernel(const int* __restrict__ lig, u64* __restrict__ bits) {
    const long total = (long)BB * WPR * NN;              // 1,048,576 words
    int  gid  = blockIdx.x * blockDim.x + threadIdx.x;
    long wid  = ((long)gid) >> 6;
    int  lane = threadIdx.x & 63;
    long nw   = ((long)gridDim.x * blockDim.x) >> 6;
    for (long o = wid; o < total; o += nw) {
        int n = (int)(o & (NN - 1));
        int w = (int)((o >> 12) & (WPR - 1));
        int b = (int)(o >> 18);
        int v = lig[((long)b * NN + n) * NN + (w << 6) + lane];
        u64 m = __ballot(v >= 1);
        if (lane == 0) bits[o] = m;
    }
}

// ----------------------------------------------------------- spmm (MFMA) ----
// grid = BB * (NN/32) = 512 blocks of 128 threads (2 waves, 2 blocks/CU).
// Wave owns one 16-row tile (row0..row0+15) x 16 features over all 4096 s,
// looped in 4 LDS chunks of 1024 s. Per word: 2 MFMAs (two 32-s k-tiles).
template<bool FIRST>
__global__ __launch_bounds__(128, 2)
void spmm_mfma(const u64* __restrict__ bits, const void* __restrict__ yin,
               float* __restrict__ yout, u16* __restrict__ youtT) {
    __shared__ u16 ys[KK * LSTR];                        // 33,024 B
    const int bid  = blockIdx.x;
    const int rblk = bid & (NN / 32 - 1);
    const int b    = bid >> 7;
    const int tid  = threadIdx.x;
    const int lane = tid & 63, W = tid >> 6;
    const int n16  = lane & 15, g = (lane >> 4) & 3;
    const int row0 = rblk * 32 + W * 16;

    f32x4v accA = {0.f, 0.f, 0.f, 0.f}, accB = {0.f, 0.f, 0.f, 0.f};
    const u64* bb = bits + (long)b * WPR * NN + row0 + n16;

    for (int ch = 0; ch < 4; ++ch) {
        // prefetch this chunk's 16 mask words (no LDS dependency)
        u64 wcs[16];
#pragma unroll
        for (int wi = 0; wi < 16; ++wi)
            wcs[wi] = bb[(long)(ch * 16 + wi) * NN];

        __syncthreads();                                 // prev chunk consumed
        if (FIRST) {
            // labels f32 [b][s][f] -> LDS bf16 [f][s] (transpose-convert)
            const float* yb = (const float*)yin + ((long)b * NN + ch * CHUNK) * KK;
#pragma unroll
            for (int it = 0; it < 32; ++it) {
                int id = it * 128 + tid;                 // 0..4095
                int s = id >> 2, q = (id & 3) * 4;
                float4 v = ((const float4*)yb)[id];
                ys[(q + 0) * LSTR + s] = (u16)bf16_rne(v.x);
                ys[(q + 1) * LSTR + s] = (u16)bf16_rne(v.y);
                ys[(q + 2) * LSTR + s] = (u16)bf16_rne(v.z);
                ys[(q + 3) * LSTR + s] = (u16)bf16_rne(v.w);
            }
        } else {
            // Y^T bf16 [b][f][n] -> LDS [f][s] (straight 16B copies)
            const u16* yt = (const u16*)yin + (long)b * KK * NN + ch * CHUNK;
#pragma unroll
            for (int it = 0; it < 16; ++it) {
                int id = it * 128 + tid;                 // 0..2047
                int f = id >> 7, c = (id & 127) * 8;
                *(s16x8*)&ys[f * LSTR + c] = *(const s16x8*)(yt + (long)f * NN + c);
            }
        }
        __syncthreads();

#pragma unroll
        for (int wi = 0; wi < 16; ++wi) {
            u64 h64 = wcs[wi] >> (g * 8);
            u32 lo8 = (u32)h64 & 0xFFu;
            u32 hi8 = ((u32)(h64 >> 32)) & 0xFFu;
            const u16* yrow = &ys[n16 * LSTR + wi * 64 + g * 8];
            s16x8 b0 = *(const s16x8*)(yrow);            // k-tile 0 (s 0..31)
            s16x8 b1 = *(const s16x8*)(yrow + 32);       // k-tile 1 (s 32..63)
            accA = __builtin_amdgcn_mfma_f32_16x16x32_bf16(expand8(lo8), b0, accA, 0, 0, 0);
            accB = __builtin_amdgcn_mfma_f32_16x16x32_bf16(expand8(hi8), b1, accB, 0, 0, 0);
        }
    }

    f32x4v acc;
#pragma unroll
    for (int r = 0; r < 4; ++r) acc[r] = accA[r] + accB[r];

    // D layout: col = lane&15 = n16 (feature), row = 4*g + r  (m89-verified)
    float* yo = yout + ((long)b * NN + row0) * KK + n16;
#pragma unroll
    for (int r = 0; r < 4; ++r) yo[(4 * g + r) * KK] = acc[r];

    // transposed bf16 for the next pass
    u16* yT = youtT + (long)b * KK * NN + (long)n16 * NN + row0 + 4 * g;
    u32 p0 = bf16_rne(acc[0]) | (bf16_rne(acc[1]) << 16);
    u32 p1 = bf16_rne(acc[2]) | (bf16_rne(acc[3]) << 16);
    *(uint2*)yT = make_uint2(p0, p1);
}

// -------------------------------------------------------------- combine -----
__global__ void combine_kernel(const float* __restrict__ Y0,
                               const float* __restrict__ Yc,   // Y1|Y2|Y3
                               const float* __restrict__ ker,  // [C][T][K]
                               float* __restrict__ out) {
    __shared__ float4 eS[3][CC][KK / 4];
    int tid = threadIdx.x;
    if (tid < CC * (KK / 4)) {
        int c = tid >> 2, k4 = tid & 3;
        const float4* kf = (const float4*)ker;
        float4 a = kf[(c * TT + 0) * (KK / 4) + k4];
        float4 d = kf[(c * TT + 1) * (KK / 4) + k4];
        float4 e = kf[(c * TT + 2) * (KK / 4) + k4];
        float4 e1, e2, e3;
        e1.x = a.x + d.x + e.x;             e1.y = a.y + d.y + e.y;
        e1.z = a.z + d.z + e.z;             e1.w = a.w + d.w + e.w;
        e2.x = a.x*d.x + a.x*e.x + d.x*e.x; e2.y = a.y*d.y + a.y*e.y + d.y*e.y;
        e2.z = a.z*d.z + a.z*e.z + d.z*e.z; e2.w = a.w*d.w + a.w*e.w + d.w*e.w;
        e3.x = a.x * d.x * e.x;             e3.y = a.y * d.y * e.y;
        e3.z = a.z * d.z * e.z;             e3.w = a.w * d.w * e.w;
        eS[0][c][k4] = e1; eS[1][c][k4] = e2; eS[2][c][k4] = e3;
    }
    __syncthreads();

    int gid = blockIdx.x * blockDim.x + tid;
    if (gid >= BB * NN * (KK / 4)) return;
    int k4 = gid & 3;
    int n  = (gid >> 2) & (NN - 1);
    int b  = gid >> 14;
    const long YSZ = (long)BB * NN * KK / 4;
    long yi = (long)(b * NN + n) * (KK / 4) + k4;
    float4 y0 = ((const float4*)Y0)[yi];
    float4 y1 = ((const float4*)Yc)[yi];
    float4 y2 = ((const float4*)Yc)[YSZ + yi];
    float4 y3 = ((const float4*)Yc)[2 * YSZ + yi];
#pragma unroll
    for (int c = 0; c < CC; ++c) {
        float4 e1 = eS[0][c][k4], e2 = eS[1][c][k4], e3 = eS[2][c][k4];
        float4 r;
        r.x = y0.x + e1.x * y1.x + e2.x * y2.x + e3.x * y3.x;
        r.y = y0.y + e1.y * y1.y + e2.y * y2.y + e3.y * y3.y;
        r.z = y0.z + e1.z * y1.z + e2.z * y2.z + e3.z * y3.z;
        r.w = y0.w + e1.w * y1.w + e2.w * y2.w + e3.w * y3.w;
        ((float4*)out)[(long)((b * CC + c) * NN + n) * (KK / 4) + k4] = r;
    }
}

// --------------------------------------------------------------- launch -----
extern "C" void kernel_launch(void* const* d_in, const int* in_sizes, int n_in,
                              void* d_out, int out_size, void* d_ws, size_t ws_size,
                              hipStream_t stream) {
    const float* labels = (const float*)d_in[0];   // [B,N,K] f32
    const int*   lig    = (const int*)d_in[1];     // [B,N,N] i32
    const float* ker    = (const float*)d_in[2];   // [C,T,K] f32
    float* out  = (float*)d_out;
    u64*   bits = (u64*)d_out;                     // 8 MB scratch, exact fit
    const long YS = (long)BB * NN * KK;            // elements per Y (f32)
    float* Y1 = (float*)d_ws;
    float* Y2 = Y1 + YS;
    float* Y3 = Y2 + YS;
    u16* Y1T = (u16*)(Y3 + YS);
    u16* Y2T = Y1T + YS;
    u16* Y3T = Y2T + YS;

    hipLaunchKernelGGL(pack_kernel, dim3(2048), dim3(256), 0, stream, lig, bits);

    dim3 sgrid(BB * (NN / 32));                    // 512 blocks
    hipLaunchKernelGGL((spmm_mfma<true>),  sgrid, dim3(128), 0, stream,
                       bits, (const void*)labels, Y1, Y1T);
    hipLaunchKernelGGL((spmm_mfma<false>), sgrid, dim3(128), 0, stream,
                       bits, (const void*)Y1T, Y2, Y2T);
    hipLaunchKernelGGL((spmm_mfma<false>), sgrid, dim3(128), 0, stream,
                       bits, (const void*)Y2T, Y3, Y3T);

    hipLaunchKernelGGL(combine_kernel, dim3(BB * NN * (KK / 4) / 256), dim3(256),
                       0, stream, labels, Y1, ker, out);
}

// Round 7
// 148.188 us; speedup vs baseline: 1.1066x; 1.1066x over previous
//
#include <hip/hip_runtime.h>

// WL-conv factorized:  out[b,c,n,k] = Y0 + e1[c,k]*Y1 + e2[c,k]*Y2 + e3[c,k]*Y3
// with Ym = M^m labels (M = thresholded adjacency, c-independent) and e_m the
// elementary symmetric polynomials of kernels[c,0..2,k]. Valid because all
// per-step operators (I + k_t ∘ M) commute.
//
// spmm on the matrix pipe, single-bf16 (error margin >500x vs threshold):
//  - 1024 blocks x 4 waves: each wave = one 16-row MFMA tile x 1024-s slice
//    (4 waves/SIMD TLP; R6's 1 wave/SIMD was the regression cause)
//  - B-frags read straight from L2-resident transposed bf16 Y^T (no LDS
//    staging, no per-chunk barriers); A-frags via in-register bit-spread
//  - 4 s-slices merged with one 3KB LDS reduce + single barrier; no atomics
//  - labels->Y0^T transpose-convert fused into pack_kernel
//
// d_out (8 MB): TRANSPOSED packed bits (word-major), overwritten by combine.
// d_ws (>=4.5 MB): Y1|Y2|Y3 f32 (3 MB) then Y0T|Y1T|Y2T bf16 (1.5 MB).

#define BB 4
#define NN 4096
#define KK 16
#define CC 8
#define TT 3
#define WPR (NN / 64)

typedef unsigned long long u64;
typedef unsigned int u32;
typedef unsigned short u16;
typedef __attribute__((ext_vector_type(8))) short s16x8;
typedef __attribute__((ext_vector_type(4))) float f32x4v;

__device__ __forceinline__ u32 bf16_rne(float f) {
    u32 u = __float_as_uint(f);
    return (u + 0x7FFFu + ((u >> 16) & 1u)) >> 16;
}

// byte (8 mask bits) -> 8 bf16 {0,1} packed in s16x8 (elem i = bit i)
__device__ __forceinline__ s16x8 expand8(u32 byt) {
    u32 n0 = byt & 0xFu, n1 = (byt >> 4) & 0xFu;
    u32 t0 = (n0 * 0x204081u) & 0x01010101u;   // bytes = bits 0..3
    u32 t1 = (n1 * 0x204081u) & 0x01010101u;   // bytes = bits 4..7
    u32 m0 = (t0 << 7) - t0;                   // bytes 0x7F / 0
    u32 m1 = (t1 << 7) - t1;
    union { u32 w[4]; s16x8 v; } u;
    u.w[0] = __builtin_amdgcn_perm(0u, m0, 0x0C010C00u) << 7;  // b0|b1<<16
    u.w[1] = __builtin_amdgcn_perm(0u, m0, 0x0C030C02u) << 7;  // b2|b3
    u.w[2] = __builtin_amdgcn_perm(0u, m1, 0x0C010C00u) << 7;  // b4|b5
    u.w[3] = __builtin_amdgcn_perm(0u, m1, 0x0C030C02u) << 7;  // b6|b7
    return u.v;
}

// ---------------------------------------------------------------- pack ------
// TRANSPOSED: bits[(b*WPR + w)*NN + n] bit j <-> (lig[b][n][w*64+j] >= 1)
// Also produces Y0^T: labels f32 [b][n][f] -> bf16 [b][f][n].
__global__ void pack_kernel(const int* __restrict__ lig, u64* __restrict__ bits,
                            const float* __restrict__ labels,
                            u16* __restrict__ y0T) {
    const long total = (long)BB * WPR * NN;              // 1,048,576 words
    int  gid  = blockIdx.x * blockDim.x + threadIdx.x;
    if (gid < BB * KK * (NN / 8)) {                      // 32768 transpose tasks
        int n8 = (gid & (NN / 8 - 1)) * 8;
        int f  = (gid >> 9) & (KK - 1);
        int b  = gid >> 13;
        const float* lp = labels + ((long)b * NN + n8) * KK + f;
        union { u16 v[8]; s16x8 s; } o;
#pragma unroll
        for (int i = 0; i < 8; ++i) o.v[i] = (u16)bf16_rne(lp[i * KK]);
        *(s16x8*)(y0T + ((long)b * KK + f) * NN + n8) = o.s;
    }
    long wid  = ((long)gid) >> 6;
    int  lane = threadIdx.x & 63;
    long nw   = ((long)gridDim.x * blockDim.x) >> 6;
    for (long o = wid; o < total; o += nw) {
        int n = (int)(o & (NN - 1));
        int w = (int)((o >> 12) & (WPR - 1));
        int b = (int)(o >> 18);
        int v = lig[((long)b * NN + n) * NN + (w << 6) + lane];
        u64 m = __ballot(v >= 1);
        if (lane == 0) bits[o] = m;
    }
}

// ----------------------------------------------------------- spmm (MFMA) ----
// grid = BB * (NN/16) = 1024 blocks of 256 threads (4 waves, 4 blocks/CU).
// Wave ss (0..3): rows row0..row0+15 x s in [ss*1024, ss*1024+1024).
// Per word wi: A = expand8(mask byte), B = 16B from global Y^T; 2 MFMAs.
// Slice partials reduced via LDS [3][4][64] (conflict-free), wave 0 stores.
template<bool WRITE_T>
__global__ __launch_bounds__(256, 4)
void spmm_mfma(const u64* __restrict__ bits, const u16* __restrict__ yinT,
               float* __restrict__ yout, u16* __restrict__ youtT) {
    __shared__ float red[3][4][64];
    const int bid  = blockIdx.x;
    const int rt   = bid & (NN / 16 - 1);
    const int b    = bid >> 8;
    const int tid  = threadIdx.x;
    const int lane = tid & 63, ss = tid >> 6;
    const int n16  = lane & 15, g = lane >> 4;
    const int row0 = rt * 16;

    // 16 mask words for this wave's s-range (128B contiguous per wi, L3-hot)
    const u64* bb = bits + ((long)b * WPR + ss * 16) * NN + row0 + n16;
    u64 wcs[16];
#pragma unroll
    for (int wi = 0; wi < 16; ++wi) wcs[wi] = bb[(long)wi * NN];

    const u16* yt = yinT + ((long)b * KK + n16) * NN + ss * 1024;
    f32x4v accA = {0.f, 0.f, 0.f, 0.f}, accB = {0.f, 0.f, 0.f, 0.f};
#pragma unroll
    for (int wi = 0; wi < 16; ++wi) {
        u64 h = wcs[wi] >> (g * 8);
        u32 lo8 = (u32)h & 0xFFu;
        u32 hi8 = ((u32)(h >> 32)) & 0xFFu;
        const u16* yr = yt + wi * 64 + g * 8;
        s16x8 b0 = *(const s16x8*)(yr);          // k-tile 0: s 0..31 of word
        s16x8 b1 = *(const s16x8*)(yr + 32);     // k-tile 1: s 32..63
        accA = __builtin_amdgcn_mfma_f32_16x16x32_bf16(expand8(lo8), b0, accA, 0, 0, 0);
        accB = __builtin_amdgcn_mfma_f32_16x16x32_bf16(expand8(hi8), b1, accB, 0, 0, 0);
    }

    f32x4v acc;
#pragma unroll
    for (int r = 0; r < 4; ++r) acc[r] = accA[r] + accB[r];

    if (ss != 0) {
#pragma unroll
        for (int r = 0; r < 4; ++r) red[ss - 1][r][lane] = acc[r];
    }
    __syncthreads();
    if (ss == 0) {
#pragma unroll
        for (int r = 0; r < 4; ++r)
            acc[r] += red[0][r][lane] + red[1][r][lane] + red[2][r][lane];

        // D: col = lane&15 = n16 (feature), row = 4*g + r  (m89-verified)
        float* yo = yout + ((long)b * NN + row0) * KK + n16;
#pragma unroll
        for (int r = 0; r < 4; ++r) yo[(4 * g + r) * KK] = acc[r];

        if (WRITE_T) {
            u16* yT = youtT + ((long)b * KK + n16) * NN + row0 + 4 * g;
            u32 p0 = bf16_rne(acc[0]) | (bf16_rne(acc[1]) << 16);
            u32 p1 = bf16_rne(acc[2]) | (bf16_rne(acc[3]) << 16);
            *(uint2*)yT = make_uint2(p0, p1);
        }
    }
}

// -------------------------------------------------------------- combine -----
__global__ void combine_kernel(const float* __restrict__ Y0,
                               const float* __restrict__ Yc,   // Y1|Y2|Y3
                               const float* __restrict__ ker,  // [C][T][K]
                               float* __restrict__ out) {
    __shared__ float4 eS[3][CC][KK / 4];
    int tid = threadIdx.x;
    if (tid < CC * (KK / 4)) {
        int c = tid >> 2, k4 = tid & 3;
        const float4* kf = (const float4*)ker;
        float4 a = kf[(c * TT + 0) * (KK / 4) + k4];
        float4 d = kf[(c * TT + 1) * (KK / 4) + k4];
        float4 e = kf[(c * TT + 2) * (KK / 4) + k4];
        float4 e1, e2, e3;
        e1.x = a.x + d.x + e.x;             e1.y = a.y + d.y + e.y;
        e1.z = a.z + d.z + e.z;             e1.w = a.w + d.w + e.w;
        e2.x = a.x*d.x + a.x*e.x + d.x*e.x; e2.y = a.y*d.y + a.y*e.y + d.y*e.y;
        e2.z = a.z*d.z + a.z*e.z + d.z*e.z; e2.w = a.w*d.w + a.w*e.w + d.w*e.w;
        e3.x = a.x * d.x * e.x;             e3.y = a.y * d.y * e.y;
        e3.z = a.z * d.z * e.z;             e3.w = a.w * d.w * e.w;
        eS[0][c][k4] = e1; eS[1][c][k4] = e2; eS[2][c][k4] = e3;
    }
    __syncthreads();

    int gid = blockIdx.x * blockDim.x + tid;
    if (gid >= BB * NN * (KK / 4)) return;
    int k4 = gid & 3;
    int n  = (gid >> 2) & (NN - 1);
    int b  = gid >> 14;
    const long YSZ = (long)BB * NN * KK / 4;
    long yi = (long)(b * NN + n) * (KK / 4) + k4;
    float4 y0 = ((const float4*)Y0)[yi];
    float4 y1 = ((const float4*)Yc)[yi];
    float4 y2 = ((const float4*)Yc)[YSZ + yi];
    float4 y3 = ((const float4*)Yc)[2 * YSZ + yi];
#pragma unroll
    for (int c = 0; c < CC; ++c) {
        float4 e1 = eS[0][c][k4], e2 = eS[1][c][k4], e3 = eS[2][c][k4];
        float4 r;
        r.x = y0.x + e1.x * y1.x + e2.x * y2.x + e3.x * y3.x;
        r.y = y0.y + e1.y * y1.y + e2.y * y2.y + e3.y * y3.y;
        r.z = y0.z + e1.z * y1.z + e2.z * y2.z + e3.z * y3.z;
        r.w = y0.w + e1.w * y1.w + e2.w * y2.w + e3.w * y3.w;
        ((float4*)out)[(long)((b * CC + c) * NN + n) * (KK / 4) + k4] = r;
    }
}

// --------------------------------------------------------------- launch -----
extern "C" void kernel_launch(void* const* d_in, const int* in_sizes, int n_in,
                              void* d_out, int out_size, void* d_ws, size_t ws_size,
                              hipStream_t stream) {
    const float* labels = (const float*)d_in[0];   // [B,N,K] f32
    const int*   lig    = (const int*)d_in[1];     // [B,N,N] i32
    const float* ker    = (const float*)d_in[2];   // [C,T,K] f32
    float* out  = (float*)d_out;
    u64*   bits = (u64*)d_out;                     // 8 MB scratch, exact fit
    const long YS = (long)BB * NN * KK;            // elements per Y
    float* Y1 = (float*)d_ws;
    float* Y2 = Y1 + YS;
    float* Y3 = Y2 + YS;
    u16* Y0T = (u16*)(Y3 + YS);
    u16* Y1T = Y0T + YS;
    u16* Y2T = Y1T + YS;

    hipLaunchKernelGGL(pack_kernel, dim3(2048), dim3(256), 0, stream,
                       lig, bits, labels, Y0T);

    dim3 sgrid(BB * (NN / 16));                    // 1024 blocks
    hipLaunchKernelGGL((spmm_mfma<true>),  sgrid, dim3(256), 0, stream,
                       bits, Y0T, Y1, Y1T);
    hipLaunchKernelGGL((spmm_mfma<true>),  sgrid, dim3(256), 0, stream,
                       bits, Y1T, Y2, Y2T);
    hipLaunchKernelGGL((spmm_mfma<false>), sgrid, dim3(256), 0, stream,
                       bits, Y2T, Y3, (u16*)nullptr);

    hipLaunchKernelGGL(combine_kernel, dim3(BB * NN * (KK / 4) / 256), dim3(256),
                       0, stream, labels, Y1, ker, out);
}

// Round 8
// 127.124 us; speedup vs baseline: 1.2900x; 1.1657x over previous
//
#include <hip/hip_runtime.h>

// WL-conv factorized:  out[b,c,n,k] = Y0 + e1[c,k]*Y1 + e2[c,k]*Y2 + e3[c,k]*Y3
// with Ym = M^m labels (M = thresholded adjacency, c-independent) and e_m the
// elementary symmetric polynomials of kernels[c,0..2,k]. Valid because all
// per-step operators (I + k_t ∘ M) commute.
//
// spmm on the matrix pipe, single-bf16 (error margin >500x vs threshold):
//  - 1024 blocks x 4 waves (4/SIMD): wave = one 16-row MFMA tile x 1024-s slice
//  - Y chained between passes in MFMA-B-FRAGMENT-SWIZZLED bf16 layout:
//      idx(f,s) = (s>>5)*512 + f*32 + ((s>>3)&3)*8 + (s&7)   [u16 units]
//    so each wave's B-fragment load is one contiguous 1KB coalesced dwordx4
//    (R7's per-lane 16B scatter was ~16x the L2 request count -> ~31us/pass)
//  - A-frags via in-register bit-spread (expand8); no LUT, no LDS staging
//  - 4 s-slices merged via 3KB LDS reduce + one barrier; no atomics
//  - labels->Y0 swizzle fused into pack_kernel
//
// d_out (8 MB): TRANSPOSED packed bits (word-major), overwritten by combine.
// d_ws (>=4.5 MB): Y1|Y2|Y3 f32 (3 MB) then Ysw0|Ysw1|Ysw2 bf16 (1.5 MB).

#define BB 4
#define NN 4096
#define KK 16
#define CC 8
#define TT 3
#define WPR (NN / 64)
#define YSWZ (KK * NN)   // u16 elements per batch in swizzled Y (65536)

typedef unsigned long long u64;
typedef unsigned int u32;
typedef unsigned short u16;
typedef __attribute__((ext_vector_type(8))) short s16x8;
typedef __attribute__((ext_vector_type(4))) float f32x4v;

__device__ __forceinline__ u32 bf16_rne(float f) {
    u32 u = __float_as_uint(f);
    return (u + 0x7FFFu + ((u >> 16) & 1u)) >> 16;
}

// byte (8 mask bits) -> 8 bf16 {0,1} packed in s16x8 (elem i = bit i)
__device__ __forceinline__ s16x8 expand8(u32 byt) {
    u32 n0 = byt & 0xFu, n1 = (byt >> 4) & 0xFu;
    u32 t0 = (n0 * 0x204081u) & 0x01010101u;   // bytes = bits 0..3
    u32 t1 = (n1 * 0x204081u) & 0x01010101u;   // bytes = bits 4..7
    u32 m0 = (t0 << 7) - t0;                   // bytes 0x7F / 0
    u32 m1 = (t1 << 7) - t1;
    union { u32 w[4]; s16x8 v; } u;
    u.w[0] = __builtin_amdgcn_perm(0u, m0, 0x0C010C00u) << 7;  // b0|b1<<16
    u.w[1] = __builtin_amdgcn_perm(0u, m0, 0x0C030C02u) << 7;  // b2|b3
    u.w[2] = __builtin_amdgcn_perm(0u, m1, 0x0C010C00u) << 7;  // b4|b5
    u.w[3] = __builtin_amdgcn_perm(0u, m1, 0x0C030C02u) << 7;  // b6|b7
    return u.v;
}

// ---------------------------------------------------------------- pack ------
// TRANSPOSED: bits[(b*WPR + w)*NN + n] bit j <-> (lig[b][n][w*64+j] >= 1)
// Also produces swizzled Y0: labels f32 [b][n][f] -> bf16 fragment layout.
__global__ void pack_kernel(const int* __restrict__ lig, u64* __restrict__ bits,
                            const float* __restrict__ labels,
                            u16* __restrict__ y0swz) {
    const long total = (long)BB * WPR * NN;              // 1,048,576 words
    int  gid  = blockIdx.x * blockDim.x + threadIdx.x;
    if (gid < BB * KK * (NN / 8)) {                      // 32768 transpose tasks
        int n8 = (gid & (NN / 8 - 1)) * 8;
        int f  = (gid >> 9) & (KK - 1);
        int b  = gid >> 13;
        const float* lp = labels + ((long)b * NN + n8) * KK + f;
        union { u16 v[8]; s16x8 s; } o;
#pragma unroll
        for (int i = 0; i < 8; ++i) o.v[i] = (u16)bf16_rne(lp[i * KK]);
        long idx = (long)b * YSWZ + (n8 >> 5) * 512 + f * 32 + ((n8 >> 3) & 3) * 8;
        *(s16x8*)(y0swz + idx) = o.s;
    }
    long wid  = ((long)gid) >> 6;
    int  lane = threadIdx.x & 63;
    long nw   = ((long)gridDim.x * blockDim.x) >> 6;
    for (long o = wid; o < total; o += nw) {
        int n = (int)(o & (NN - 1));
        int w = (int)((o >> 12) & (WPR - 1));
        int b = (int)(o >> 18);
        int v = lig[((long)b * NN + n) * NN + (w << 6) + lane];
        u64 m = __ballot(v >= 1);
        if (lane == 0) bits[o] = m;
    }
}

// ----------------------------------------------------------- spmm (MFMA) ----
// grid = BB * (NN/16) = 1024 blocks of 256 threads (4 waves, 4 blocks/CU).
// Wave ss (0..3): rows row0..row0+15 x s in [ss*1024, ss*1024+1024).
// Per word wi: A = expand8(mask byte); B = one coalesced 1KB fragment load
// per k-tile from swizzled Y. Slices reduced via LDS, wave 0 stores.
template<bool WRITE_T>
__global__ __launch_bounds__(256, 4)
void spmm_mfma(const u64* __restrict__ bits, const u16* __restrict__ yswzin,
               float* __restrict__ yout, u16* __restrict__ yswzout) {
    __shared__ float red[3][4][64];
    const int bid  = blockIdx.x;
    const int rt   = bid & (NN / 16 - 1);
    const int b    = bid >> 8;
    const int tid  = threadIdx.x;
    const int lane = tid & 63, ss = tid >> 6;
    const int n16  = lane & 15, g = lane >> 4;
    const int row0 = rt * 16;

    // 16 mask words for this wave's s-range (128B contiguous per wi)
    const u64* bb = bits + ((long)b * WPR + ss * 16) * NN + row0 + n16;
    u64 wcs[16];
#pragma unroll
    for (int wi = 0; wi < 16; ++wi) wcs[wi] = bb[(long)wi * NN];

    // swizzled B: word w fragment base = w*1024 + n16*32 + g*8 (b1 at +512)
    const u16* yb = yswzin + (long)b * YSWZ + (ss * 16) * 1024 + n16 * 32 + g * 8;
    f32x4v accA = {0.f, 0.f, 0.f, 0.f}, accB = {0.f, 0.f, 0.f, 0.f};
#pragma unroll
    for (int wi = 0; wi < 16; ++wi) {
        u64 h = wcs[wi] >> (g * 8);
        u32 lo8 = (u32)h & 0xFFu;
        u32 hi8 = ((u32)(h >> 32)) & 0xFFu;
        const u16* yr = yb + wi * 1024;
        s16x8 b0 = *(const s16x8*)(yr);          // k-tile 0: s 0..31 of word
        s16x8 b1 = *(const s16x8*)(yr + 512);    // k-tile 1: s 32..63
        accA = __builtin_amdgcn_mfma_f32_16x16x32_bf16(expand8(lo8), b0, accA, 0, 0, 0);
        accB = __builtin_amdgcn_mfma_f32_16x16x32_bf16(expand8(hi8), b1, accB, 0, 0, 0);
    }

    f32x4v acc;
#pragma unroll
    for (int r = 0; r < 4; ++r) acc[r] = accA[r] + accB[r];

    if (ss != 0) {
#pragma unroll
        for (int r = 0; r < 4; ++r) red[ss - 1][r][lane] = acc[r];
    }
    __syncthreads();
    if (ss == 0) {
#pragma unroll
        for (int r = 0; r < 4; ++r)
            acc[r] += red[0][r][lane] + red[1][r][lane] + red[2][r][lane];

        // D: col = lane&15 = n16 (feature), row = 4*g + r  (m89-verified)
        float* yo = yout + ((long)b * NN + row0) * KK + n16;
#pragma unroll
        for (int r = 0; r < 4; ++r) yo[(4 * g + r) * KK] = acc[r];

        if (WRITE_T) {
            int s0 = row0 + 4 * g;               // 4 consecutive s, one chunk
            long idx = (long)b * YSWZ + (s0 >> 5) * 512 + n16 * 32 +
                       ((s0 >> 3) & 3) * 8 + (s0 & 7);
            u32 p0 = bf16_rne(acc[0]) | (bf16_rne(acc[1]) << 16);
            u32 p1 = bf16_rne(acc[2]) | (bf16_rne(acc[3]) << 16);
            *(uint2*)(yswzout + idx) = make_uint2(p0, p1);
        }
    }
}

// -------------------------------------------------------------- combine -----
__global__ void combine_kernel(const float* __restrict__ Y0,
                               const float* __restrict__ Yc,   // Y1|Y2|Y3
                               const float* __restrict__ ker,  // [C][T][K]
                               float* __restrict__ out) {
    __shared__ float4 eS[3][CC][KK / 4];
    int tid = threadIdx.x;
    if (tid < CC * (KK / 4)) {
        int c = tid >> 2, k4 = tid & 3;
        const float4* kf = (const float4*)ker;
        float4 a = kf[(c * TT + 0) * (KK / 4) + k4];
        float4 d = kf[(c * TT + 1) * (KK / 4) + k4];
        float4 e = kf[(c * TT + 2) * (KK / 4) + k4];
        float4 e1, e2, e3;
        e1.x = a.x + d.x + e.x;             e1.y = a.y + d.y + e.y;
        e1.z = a.z + d.z + e.z;             e1.w = a.w + d.w + e.w;
        e2.x = a.x*d.x + a.x*e.x + d.x*e.x; e2.y = a.y*d.y + a.y*e.y + d.y*e.y;
        e2.z = a.z*d.z + a.z*e.z + d.z*e.z; e2.w = a.w*d.w + a.w*e.w + d.w*e.w;
        e3.x = a.x * d.x * e.x;             e3.y = a.y * d.y * e.y;
        e3.z = a.z * d.z * e.z;             e3.w = a.w * d.w * e.w;
        eS[0][c][k4] = e1; eS[1][c][k4] = e2; eS[2][c][k4] = e3;
    }
    __syncthreads();

    int gid = blockIdx.x * blockDim.x + tid;
    if (gid >= BB * NN * (KK / 4)) return;
    int k4 = gid & 3;
    int n  = (gid >> 2) & (NN - 1);
    int b  = gid >> 14;
    const long YSZ = (long)BB * NN * KK / 4;
    long yi = (long)(b * NN + n) * (KK / 4) + k4;
    float4 y0 = ((const float4*)Y0)[yi];
    float4 y1 = ((const float4*)Yc)[yi];
    float4 y2 = ((const float4*)Yc)[YSZ + yi];
    float4 y3 = ((const float4*)Yc)[2 * YSZ + yi];
#pragma unroll
    for (int c = 0; c < CC; ++c) {
        float4 e1 = eS[0][c][k4], e2 = eS[1][c][k4], e3 = eS[2][c][k4];
        float4 r;
        r.x = y0.x + e1.x * y1.x + e2.x * y2.x + e3.x * y3.x;
        r.y = y0.y + e1.y * y1.y + e2.y * y2.y + e3.y * y3.y;
        r.z = y0.z + e1.z * y1.z + e2.z * y2.z + e3.z * y3.z;
        r.w = y0.w + e1.w * y1.w + e2.w * y2.w + e3.w * y3.w;
        ((float4*)out)[(long)((b * CC + c) * NN + n) * (KK / 4) + k4] = r;
    }
}

// --------------------------------------------------------------- launch -----
extern "C" void kernel_launch(void* const* d_in, const int* in_sizes, int n_in,
                              void* d_out, int out_size, void* d_ws, size_t ws_size,
                              hipStream_t stream) {
    const float* labels = (const float*)d_in[0];   // [B,N,K] f32
    const int*   lig    = (const int*)d_in[1];     // [B,N,N] i32
    const float* ker    = (const float*)d_in[2];   // [C,T,K] f32
    float* out  = (float*)d_out;
    u64*   bits = (u64*)d_out;                     // 8 MB scratch, exact fit
    const long YS = (long)BB * NN * KK;            // elements per Y
    float* Y1 = (float*)d_ws;
    float* Y2 = Y1 + YS;
    float* Y3 = Y2 + YS;
    u16* Ysw0 = (u16*)(Y3 + YS);
    u16* Ysw1 = Ysw0 + YS;
    u16* Ysw2 = Ysw1 + YS;

    hipLaunchKernelGGL(pack_kernel, dim3(2048), dim3(256), 0, stream,
                       lig, bits, labels, Ysw0);

    dim3 sgrid(BB * (NN / 16));                    // 1024 blocks
    hipLaunchKernelGGL((spmm_mfma<true>),  sgrid, dim3(256), 0, stream,
                       bits, Ysw0, Y1, Ysw1);
    hipLaunchKernelGGL((spmm_mfma<true>),  sgrid, dim3(256), 0, stream,
                       bits, Ysw1, Y2, Ysw2);
    hipLaunchKernelGGL((spmm_mfma<false>), sgrid, dim3(256), 0, stream,
                       bits, Ysw2, Y3, (u16*)nullptr);

    hipLaunchKernelGGL(combine_kernel, dim3(BB * NN * (KK / 4) / 256), dim3(256),
                       0, stream, labels, Y1, ker, out);
}